// Round 4
// baseline (652.995 us; speedup 1.0000x reference)
//
#include <hip/hip_runtime.h>
#include <math.h>

// BeliveMapsNMS: 7x7 same-padded max-pool NMS on [32,4,512,512] f32.
// Outputs (concat flat): mask(0/1 f32), scores_abs, scores_rel.
// R4: barrier-free streaming nms. One wave = 32-row x 512-col stripe, rolls
// down in 4-row batches. Horizontal 7-max via shuffle van Herk (verified R3),
// 6-row rowmax history + 3-row raw lag in registers. No LDS, no syncthreads.
// Next-batch loads prefetched before current-batch compute. NT stores.

#define H 512
#define W 512
#define PLANE_ELEMS (H * W)   // 262144
#define S 32                  // rows per wave
#define NEG_INF (-INFINITY)

typedef float v4f __attribute__((ext_vector_type(4)));

struct Row8 { float4 lo, hi; };  // 8 contiguous cols per lane

__device__ __forceinline__ float4 vmax4(float4 a, float4 b) {
    return make_float4(fmaxf(a.x, b.x), fmaxf(a.y, b.y), fmaxf(a.z, b.z), fmaxf(a.w, b.w));
}
__device__ __forceinline__ Row8 vmax8(Row8 a, Row8 b) {
    Row8 r; r.lo = vmax4(a.lo, b.lo); r.hi = vmax4(a.hi, b.hi); return r;
}

__device__ __forceinline__ void nt_store4(float* p, float a, float b, float c, float d) {
    v4f v = {a, b, c, d};
    __builtin_nontemporal_store(v, (v4f*)p);
}

// Load one full row: lane covers cols 8*lane..8*lane+7 (v0=row[2l], v1=row[2l+1]).
// Wave-uniform gy -> no divergence on the OOB branch.
__device__ __forceinline__ Row8 loadRow(const float* __restrict__ pin, int gy, int lane) {
    Row8 r;
    if (gy >= 0 && gy < H) {
        const float4* row = (const float4*)(pin + (size_t)gy * W);
        r.lo = row[lane * 2];
        r.hi = row[lane * 2 + 1];
    } else {
        r.lo = r.hi = make_float4(NEG_INF, NEG_INF, NEG_INF, NEG_INF);
    }
    return r;
}

// Horizontal 7-max (van Herk) with shuffle halo. Verified in R3.
__device__ __forceinline__ Row8 hmax7(Row8 v, int lane) {
    float l0 = __shfl_up(v.hi.y, 1, 64), l1 = __shfl_up(v.hi.z, 1, 64), l2 = __shfl_up(v.hi.w, 1, 64);
    float r0 = __shfl_down(v.lo.x, 1, 64), r1 = __shfl_down(v.lo.y, 1, 64), r2 = __shfl_down(v.lo.z, 1, 64);
    if (lane == 0) { l0 = NEG_INF; l1 = NEG_INF; l2 = NEG_INF; }
    if (lane == 63) { r0 = NEG_INF; r1 = NEG_INF; r2 = NEG_INF; }
    float a[14] = {l0, l1, l2, v.lo.x, v.lo.y, v.lo.z, v.lo.w,
                   v.hi.x, v.hi.y, v.hi.z, v.hi.w, r0, r1, r2};
    float A[7];
    A[6] = a[6];
    #pragma unroll
    for (int j = 5; j >= 0; --j) A[j] = fmaxf(a[j], A[j + 1]);
    float rm[8];
    rm[0] = A[0];
    float B = a[7];
    rm[1] = fmaxf(A[1], B);
    #pragma unroll
    for (int j = 2; j <= 6; ++j) { B = fmaxf(B, a[6 + j]); rm[j] = fmaxf(A[j], B); }
    B = fmaxf(B, a[13]);
    rm[7] = B;
    Row8 out;
    out.lo = make_float4(rm[0], rm[1], rm[2], rm[3]);
    out.hi = make_float4(rm[4], rm[5], rm[6], rm[7]);
    return out;
}

__device__ __forceinline__ void emitRow(float* __restrict__ om, float* __restrict__ oa,
                                        float* __restrict__ orl, size_t off,
                                        Row8 m, Row8 ctr, float rel_thr, float inv_vmax) {
    const bool p0 = (m.lo.x == ctr.lo.x) & (ctr.lo.x > 0.2f) & (ctr.lo.x > rel_thr);
    const bool p1 = (m.lo.y == ctr.lo.y) & (ctr.lo.y > 0.2f) & (ctr.lo.y > rel_thr);
    const bool p2 = (m.lo.z == ctr.lo.z) & (ctr.lo.z > 0.2f) & (ctr.lo.z > rel_thr);
    const bool p3 = (m.lo.w == ctr.lo.w) & (ctr.lo.w > 0.2f) & (ctr.lo.w > rel_thr);
    const bool q0 = (m.hi.x == ctr.hi.x) & (ctr.hi.x > 0.2f) & (ctr.hi.x > rel_thr);
    const bool q1 = (m.hi.y == ctr.hi.y) & (ctr.hi.y > 0.2f) & (ctr.hi.y > rel_thr);
    const bool q2 = (m.hi.z == ctr.hi.z) & (ctr.hi.z > 0.2f) & (ctr.hi.z > rel_thr);
    const bool q3 = (m.hi.w == ctr.hi.w) & (ctr.hi.w > 0.2f) & (ctr.hi.w > rel_thr);
    const float a0 = p0 ? ctr.lo.x : 0.0f, a1 = p1 ? ctr.lo.y : 0.0f;
    const float a2 = p2 ? ctr.lo.z : 0.0f, a3 = p3 ? ctr.lo.w : 0.0f;
    const float b0 = q0 ? ctr.hi.x : 0.0f, b1 = q1 ? ctr.hi.y : 0.0f;
    const float b2 = q2 ? ctr.hi.z : 0.0f, b3 = q3 ? ctr.hi.w : 0.0f;
    nt_store4(om + off,     p0 ? 1.0f : 0.0f, p1 ? 1.0f : 0.0f, p2 ? 1.0f : 0.0f, p3 ? 1.0f : 0.0f);
    nt_store4(om + off + 4, q0 ? 1.0f : 0.0f, q1 ? 1.0f : 0.0f, q2 ? 1.0f : 0.0f, q3 ? 1.0f : 0.0f);
    nt_store4(oa + off,     a0, a1, a2, a3);
    nt_store4(oa + off + 4, b0, b1, b2, b3);
    nt_store4(orl + off,     a0 * inv_vmax, a1 * inv_vmax, a2 * inv_vmax, a3 * inv_vmax);
    nt_store4(orl + off + 4, b0 * inv_vmax, b1 * inv_vmax, b2 * inv_vmax, b3 * inv_vmax);
}

// ---------------- Pass 1: per-plane max ----------------
__global__ __launch_bounds__(256) void vmax_kernel(const float* __restrict__ in,
                                                   unsigned int* __restrict__ vmax_bits) {
    const int q = blockIdx.x;      // 4 quarters
    const int plane = blockIdx.y;  // 128 planes
    const float4* p = (const float4*)(in + (size_t)plane * PLANE_ELEMS + q * (PLANE_ELEMS / 4));
    float m = 0.0f;  // inputs in [0,1): non-negative
    const int nvec = PLANE_ELEMS / 4 / 4;
    for (int i = threadIdx.x; i < nvec; i += 256) {
        float4 v = p[i];
        m = fmaxf(m, fmaxf(fmaxf(v.x, v.y), fmaxf(v.z, v.w)));
    }
    #pragma unroll
    for (int o = 32; o > 0; o >>= 1) m = fmaxf(m, __shfl_down(m, o, 64));
    __shared__ float s[4];
    if ((threadIdx.x & 63) == 0) s[threadIdx.x >> 6] = m;
    __syncthreads();
    if (threadIdx.x == 0) {
        m = fmaxf(fmaxf(s[0], s[1]), fmaxf(s[2], s[3]));
        atomicMax(&vmax_bits[plane], __float_as_uint(m));  // non-neg: uint order == float order
    }
}

// ---------------- Pass 2: streaming NMS ----------------
__global__ __launch_bounds__(256, 2) void nms_kernel(const float* __restrict__ in,
                                                     const unsigned int* __restrict__ vmax_bits,
                                                     float* __restrict__ out, int N) {
    const int plane = blockIdx.y;
    const int wid = threadIdx.x >> 6;
    const int lane = threadIdx.x & 63;
    const int r0 = (blockIdx.x * 4 + wid) * S;   // stripe start row for this wave
    const float* pin = in + (size_t)plane * PLANE_ELEMS;

    const float vmaxv = __uint_as_float(vmax_bits[plane]);
    const float rel_thr = 0.05f * vmaxv;
    const float inv_vmax = 1.0f / vmaxv;

    float* __restrict__ omask = out;
    float* __restrict__ oabs = out + (size_t)N;
    float* __restrict__ orel = out + 2 * (size_t)N;
    const size_t planeBase = (size_t)plane * PLANE_ELEMS;
    const int c8 = lane << 3;

    // Prologue: hist = rowmax of rows r0-3..r0+2; raw lag = rows r0..r0+2.
    Row8 hist[6], raw[3], fresh[4];
    #pragma unroll
    for (int j = 0; j < 6; ++j) {
        Row8 rr = loadRow(pin, r0 - 3 + j, lane);
        hist[j] = hmax7(rr, lane);
        if (j >= 3) raw[j - 3] = rr;
    }
    #pragma unroll
    for (int j = 0; j < 4; ++j) fresh[j] = loadRow(pin, r0 + 3 + j, lane);

    #pragma unroll
    for (int k = 0; k < S / 4; ++k) {
        const int R = r0 + 4 * k;
        // Prefetch next batch's raw rows before computing this batch.
        Row8 nxt[4];
        if (k < S / 4 - 1) {
            #pragma unroll
            for (int j = 0; j < 4; ++j) nxt[j] = loadRow(pin, R + 7 + j, lane);
        }
        // Horizontal 7-max of fresh rows R+3..R+6.
        Row8 hm[4];
        #pragma unroll
        for (int j = 0; j < 4; ++j) hm[j] = hmax7(fresh[j], lane);
        // Vertical van Herk: out[R+i] = max(hm[R+i-3 .. R+i+3]).
        Row8 sfx = vmax8(hist[4], hist[5]);
        Row8 A3 = vmax8(hist[3], sfx);
        Row8 A2 = vmax8(hist[2], A3);
        Row8 A1 = vmax8(hist[1], A2);
        Row8 A0 = vmax8(hist[0], A1);
        Row8 B0 = hm[0];
        Row8 B1 = vmax8(B0, hm[1]);
        Row8 B2 = vmax8(B1, hm[2]);
        Row8 B3 = vmax8(B2, hm[3]);
        const size_t off = planeBase + (size_t)R * W + c8;
        emitRow(omask, oabs, orel, off,         vmax8(A0, B0), raw[0],  rel_thr, inv_vmax);
        emitRow(omask, oabs, orel, off + W,     vmax8(A1, B1), raw[1],  rel_thr, inv_vmax);
        emitRow(omask, oabs, orel, off + 2 * W, vmax8(A2, B2), raw[2],  rel_thr, inv_vmax);
        emitRow(omask, oabs, orel, off + 3 * W, vmax8(A3, B3), fresh[0], rel_thr, inv_vmax);
        // Rotate state (register renaming under full unroll).
        hist[0] = hist[4]; hist[1] = hist[5];
        hist[2] = hm[0]; hist[3] = hm[1]; hist[4] = hm[2]; hist[5] = hm[3];
        raw[0] = fresh[1]; raw[1] = fresh[2]; raw[2] = fresh[3];
        fresh[0] = nxt[0]; fresh[1] = nxt[1]; fresh[2] = nxt[2]; fresh[3] = nxt[3];
    }
}

extern "C" void kernel_launch(void* const* d_in, const int* in_sizes, int n_in,
                              void* d_out, int out_size, void* d_ws, size_t ws_size,
                              hipStream_t stream) {
    const float* in = (const float*)d_in[0];
    float* out = (float*)d_out;
    const int N = in_sizes[0];           // 33554432
    const int planes = N / PLANE_ELEMS;  // 128

    unsigned int* vmax_bits = (unsigned int*)d_ws;
    (void)hipMemsetAsync(vmax_bits, 0, planes * sizeof(unsigned int), stream);

    vmax_kernel<<<dim3(4, planes), 256, 0, stream>>>(in, vmax_bits);
    // 4 waves/block, each wave a 32-row stripe: block covers 128 rows.
    nms_kernel<<<dim3(H / (4 * S), planes), 256, 0, stream>>>(in, vmax_bits, out, N);
}